// Round 1
// baseline (685.116 us; speedup 1.0000x reference)
//
#include <hip/hip_runtime.h>
#include <math.h>

// Problem constants (from reference)
#define NSENT 131072
#define NBAGS 8192
#define DIM   690
#define NCLS  53
#define PAIRS 345   // DIM/2 (rows are 8B-aligned: 690*4=2760 % 8 == 0)

// ---------------------------------------------------------------------------
// Kernel 0: comb[q][d] = attention_weight[q][d] * relation_weight[q][d]
// 53*690 = 36570 elements -> tiny, L2-resident table for the main kernel.
// ---------------------------------------------------------------------------
__global__ void comb_kernel(const float* __restrict__ att,
                            const float* __restrict__ rel,
                            float* __restrict__ comb) {
    int i = blockIdx.x * 256 + threadIdx.x;
    if (i < NCLS * DIM) comb[i] = att[i] * rel[i];
}

// ---------------------------------------------------------------------------
// Main kernel: ONE WAVE PER BAG (4 bags per 256-thread block, no LDS, no
// __syncthreads). 2048 blocks * 4 waves = 8192 waves = exactly 32 waves/CU
// at <=64 VGPR -> full occupancy; latency of the per-sentence dependent
// chain is hidden by TLP instead of exposed at barriers.
//
// Online softmax with defer-max (rescale only when logit - m > 8, a
// wave-uniform branch; e bounded by e^8, harmless in fp32):
//   common path per sentence: dot(12 FMA) + 6-shfl reduce + 1 __expf + 12 FMA
// x is read from HBM exactly once.
// ---------------------------------------------------------------------------
template <bool USE_COMB>
__global__ __launch_bounds__(256, 8) void bag_attn_wave_kernel(
        const float* __restrict__ x,
        const float* __restrict__ rel,
        const float* __restrict__ att,
        const float* __restrict__ bias,
        const int*   __restrict__ query,
        const int*   __restrict__ scope,
        const float* __restrict__ comb,
        float*       __restrict__ out) {
    const int tid  = threadIdx.x;
    const int wave = tid >> 6;
    const int lane = tid & 63;
    const int b    = blockIdx.x * 4 + wave;   // one bag per wave

    const int start = scope[b];
    const int end   = scope[b + 1];

    // online-softmax state (acc distributed across lanes: lane owns pairs
    // p = lane + 64k, k = 0..5; p < 345)
    float2 acc[6];
#pragma unroll
    for (int k = 0; k < 6; ++k) acc[k] = make_float2(0.f, 0.f);
    float m = -INFINITY;
    float l = 0.f;

    for (int i = start; i < end; ++i) {
        const float2* xrow = (const float2*)(x + (size_t)i * DIM);
        const int q = query[i];

        float2 xv[6];
        float partial = 0.f;
        if (USE_COMB) {
            const float2* crow = (const float2*)(comb + (size_t)q * DIM);
#pragma unroll
            for (int k = 0; k < 6; ++k) {
                const int p = lane + 64 * k;
                if (p < PAIRS) {
                    xv[k] = xrow[p];
                    const float2 cv = crow[p];
                    partial = fmaf(xv[k].x, cv.x, partial);
                    partial = fmaf(xv[k].y, cv.y, partial);
                } else {
                    xv[k] = make_float2(0.f, 0.f);
                }
            }
        } else {
            const float2* rrow = (const float2*)(rel + (size_t)q * DIM);
            const float2* arow = (const float2*)(att + (size_t)q * DIM);
#pragma unroll
            for (int k = 0; k < 6; ++k) {
                const int p = lane + 64 * k;
                if (p < PAIRS) {
                    xv[k] = xrow[p];
                    const float2 rv = rrow[p];
                    const float2 av = arow[p];
                    partial = fmaf(xv[k].x, rv.x * av.x, partial);
                    partial = fmaf(xv[k].y, rv.y * av.y, partial);
                } else {
                    xv[k] = make_float2(0.f, 0.f);
                }
            }
        }

        // wave-wide sum (64 lanes) -> logit broadcast to all lanes
#pragma unroll
        for (int off = 32; off >= 1; off >>= 1)
            partial += __shfl_xor(partial, off, 64);

        // defer-max online softmax. First iter: d = +inf -> rescale branch
        // with r = __expf(-inf) = 0 -> l = 1, acc = xv, m = logit.
        const float d = partial - m;
        if (d <= 8.0f) {                       // wave-uniform condition
            const float e = __expf(d);         // bounded by e^8
#pragma unroll
            for (int k = 0; k < 6; ++k) {
                acc[k].x = fmaf(e, xv[k].x, acc[k].x);
                acc[k].y = fmaf(e, xv[k].y, acc[k].y);
            }
            l += e;
        } else {
            const float r = __expf(-d);        // exp(m - logit) < e^-8
#pragma unroll
            for (int k = 0; k < 6; ++k) {
                acc[k].x = fmaf(acc[k].x, r, xv[k].x);
                acc[k].y = fmaf(acc[k].y, r, xv[k].y);
            }
            l = fmaf(l, r, 1.f);
            m = partial;
        }
    }

    // ---- epilogue: out[b][c] = dot(acc, rel[c]) / l + bias[c] ----
    // bags are never empty (scope strictly increasing) -> l > 0.
    const float inv = 1.f / l;
    float res = (lane < NCLS) ? bias[lane] : 0.f;

    // 26 class-pairs: two independent reduce chains per iteration for ILP.
#pragma unroll 1
    for (int c = 0; c < NCLS - 1; c += 2) {
        const float2* r0 = (const float2*)(rel + (size_t)c * DIM);
        const float2* r1 = (const float2*)(rel + (size_t)(c + 1) * DIM);
        float p0 = 0.f, p1 = 0.f;
#pragma unroll
        for (int k = 0; k < 6; ++k) {
            const int p = lane + 64 * k;
            if (p < PAIRS) {
                const float2 v0 = r0[p];
                const float2 v1 = r1[p];
                p0 = fmaf(v0.x, acc[k].x, p0);
                p0 = fmaf(v0.y, acc[k].y, p0);
                p1 = fmaf(v1.x, acc[k].x, p1);
                p1 = fmaf(v1.y, acc[k].y, p1);
            }
        }
#pragma unroll
        for (int off = 32; off >= 1; off >>= 1) {
            p0 += __shfl_xor(p0, off, 64);
            p1 += __shfl_xor(p1, off, 64);
        }
        if (lane == c)     res = fmaf(p0, inv, res);
        if (lane == c + 1) res = fmaf(p1, inv, res);
    }
    {   // final odd class c = 52
        const int c = NCLS - 1;
        const float2* r0 = (const float2*)(rel + (size_t)c * DIM);
        float p0 = 0.f;
#pragma unroll
        for (int k = 0; k < 6; ++k) {
            const int p = lane + 64 * k;
            if (p < PAIRS) {
                const float2 v0 = r0[p];
                p0 = fmaf(v0.x, acc[k].x, p0);
                p0 = fmaf(v0.y, acc[k].y, p0);
            }
        }
#pragma unroll
        for (int off = 32; off >= 1; off >>= 1)
            p0 += __shfl_xor(p0, off, 64);
        if (lane == c) res = fmaf(p0, inv, res);
    }

    // one coalesced 212B store per bag instead of 53 lane-0 scalar stores
    if (lane < NCLS) out[(size_t)b * NCLS + lane] = res;
}

extern "C" void kernel_launch(void* const* d_in, const int* in_sizes, int n_in,
                              void* d_out, int out_size, void* d_ws, size_t ws_size,
                              hipStream_t stream) {
    const float* x     = (const float*)d_in[0];   // [131072, 690]
    const float* rel   = (const float*)d_in[1];   // [53, 690]
    const float* att   = (const float*)d_in[2];   // [53, 690]
    const float* bias  = (const float*)d_in[3];   // [53]
    const int*   query = (const int*)d_in[4];     // [131072]
    const int*   scope = (const int*)d_in[5];     // [8193]
    float*       out   = (float*)d_out;           // [8192, 53]

    const size_t comb_bytes = (size_t)NCLS * DIM * sizeof(float);
    if (ws_size >= comb_bytes) {
        float* comb = (float*)d_ws;
        comb_kernel<<<(NCLS * DIM + 255) / 256, 256, 0, stream>>>(att, rel, comb);
        bag_attn_wave_kernel<true><<<NBAGS / 4, 256, 0, stream>>>(
            x, rel, att, bias, query, scope, comb, out);
    } else {
        bag_attn_wave_kernel<false><<<NBAGS / 4, 256, 0, stream>>>(
            x, rel, att, bias, query, scope, nullptr, out);
    }
}